// Round 4
// baseline (16.200 us; speedup 1.0000x reference)
//
#include <hip/hip_runtime.h>

// Gather: out[b, j, :] = x[b, idx[b, j], :]
// x:   [B=16, S=8192, D=256] float32
// idx: [B=16, REF_LEN=2048] int32 (sorted per batch)
// out: [B=16, REF_LEN=2048, D=256] float32
//
// One wave owns one output row per k-phase (64 lanes x float4 = 1024B = row).
// 8 rows per wave (PER_THREAD=8) with phase-split scalar-idx-load /
// vector-gather / nontemporal-store for deep MLP.

typedef float vfloat4 __attribute__((ext_vector_type(4)));

constexpr int B = 16;
constexpr int S = 8192;
constexpr int D = 256;
constexpr int REF_LEN = 2048;
constexpr int ROWS = B * REF_LEN;              // 32768 rows
constexpr int THREADS = 256;
constexpr int BLOCKS = 1024;
constexpr int WAVES = BLOCKS * THREADS / 64;   // 4096 waves
constexpr int PER_THREAD = ROWS / WAVES;       // 8 rows per wave

__global__ __launch_bounds__(THREADS) void gather_rows_kernel(
    const vfloat4* __restrict__ x,
    const int* __restrict__ idx,
    vfloat4* __restrict__ out) {
    const int tid = blockIdx.x * THREADS + threadIdx.x;
    const int lane = threadIdx.x & 63;
    const int wave0 = tid >> 6;                // first row owned by this wave

    // Phase 1: idx loads — wave-uniform address, force scalar via readfirstlane
    int srow[PER_THREAD];
    #pragma unroll
    for (int k = 0; k < PER_THREAD; ++k) {
        const int row = wave0 + k * WAVES;
        const int urow = __builtin_amdgcn_readfirstlane(row);
        srow[k] = idx[urow];                   // s_load + broadcast
    }

    // Phase 2: 8 independent row-gathers in flight
    vfloat4 v[PER_THREAD];
    #pragma unroll
    for (int k = 0; k < PER_THREAD; ++k) {
        const int row = wave0 + k * WAVES;
        const int b = row >> 11;               // / REF_LEN
        const size_t src_off = (((size_t)(b * S + srow[k])) << 6) + lane;
        v[k] = x[src_off];
    }

    // Phase 3: nontemporal stores (write-once output)
    #pragma unroll
    for (int k = 0; k < PER_THREAD; ++k) {
        const int row = wave0 + k * WAVES;
        __builtin_nontemporal_store(v[k], &out[((size_t)row << 6) + lane]);
    }
}

extern "C" void kernel_launch(void* const* d_in, const int* in_sizes, int n_in,
                              void* d_out, int out_size, void* d_ws, size_t ws_size,
                              hipStream_t stream) {
    const vfloat4* x = (const vfloat4*)d_in[0];
    const int* idx = (const int*)d_in[1];
    vfloat4* out = (vfloat4*)d_out;

    gather_rows_kernel<<<BLOCKS, THREADS, 0, stream>>>(x, idx, out);
}

// Round 5
// 14.257 us; speedup vs baseline: 1.1362x; 1.1362x over previous
//
#include <hip/hip_runtime.h>

// Gather: out[b, j, :] = x[b, idx[b, j], :]
// x:   [B=16, S=8192, D=256] float32
// idx: [B=16, REF_LEN=2048] int32 (sorted per batch)
// out: [B=16, REF_LEN=2048, D=256] float32
//
// 4096 blocks x 256 threads (16384 waves), 2 float4 per thread,
// phase-split load/store for MLP. Max TLP + 2-deep ILP.

typedef float vfloat4 __attribute__((ext_vector_type(4)));

constexpr int B = 16;
constexpr int S = 8192;
constexpr int D = 256;
constexpr int REF_LEN = 2048;
constexpr int ROWS = B * REF_LEN;              // 32768 rows
constexpr int F4_PER_ROW = D / 4;              // 64 float4 per row
constexpr int TOTAL_F4 = ROWS * F4_PER_ROW;    // 2,097,152
constexpr int THREADS = 256;
constexpr int BLOCKS = 4096;
constexpr int PER_THREAD = TOTAL_F4 / (THREADS * BLOCKS);  // 2
constexpr int STRIDE = THREADS * BLOCKS;       // 1,048,576

__global__ __launch_bounds__(THREADS) void gather_rows_kernel(
    const vfloat4* __restrict__ x,
    const int* __restrict__ idx,
    vfloat4* __restrict__ out) {
    const int tid = blockIdx.x * THREADS + threadIdx.x;

    int e[PER_THREAD];
    int src[PER_THREAD];
    vfloat4 v[PER_THREAD];

    // Phase 1: idx loads (wave-uniform address per k)
    #pragma unroll
    for (int k = 0; k < PER_THREAD; ++k) {
        e[k] = tid + k * STRIDE;
        src[k] = idx[e[k] >> 6];
    }

    // Phase 2: independent gather chains in flight
    #pragma unroll
    for (int k = 0; k < PER_THREAD; ++k) {
        const int row = e[k] >> 6;             // global output row
        const int b = row >> 11;               // / REF_LEN
        const int lane_in_row = e[k] & (F4_PER_ROW - 1);
        const size_t src_off = (((size_t)(b * S + src[k])) << 6) + lane_in_row;
        v[k] = x[src_off];
    }

    // Phase 3: nontemporal stores (write-once output)
    #pragma unroll
    for (int k = 0; k < PER_THREAD; ++k) {
        __builtin_nontemporal_store(v[k], &out[e[k]]);
    }
}

extern "C" void kernel_launch(void* const* d_in, const int* in_sizes, int n_in,
                              void* d_out, int out_size, void* d_ws, size_t ws_size,
                              hipStream_t stream) {
    const vfloat4* x = (const vfloat4*)d_in[0];
    const int* idx = (const int*)d_in[1];
    vfloat4* out = (vfloat4*)d_out;

    gather_rows_kernel<<<BLOCKS, THREADS, 0, stream>>>(x, idx, out);
}